// Round 2
// baseline (464.592 us; speedup 1.0000x reference)
//
#include <hip/hip_runtime.h>
#include <math.h>

#define NUM_STEPS 50

// Force a wave-uniform float into an SGPR so VOP3 fmas read it as the one
// allowed scalar operand (frees VGPRs, kills coefficient moves).
__device__ __forceinline__ float sbc(float x) {
    return __int_as_float(__builtin_amdgcn_readfirstlane(__float_as_int(x)));
}

// f(z) = (a - b*|z|^2) * z   (complex); |z|^2 exactly real as in the reference
#define FEVAL(ZR, ZI, KR, KI, AR, AI, BR, BI)            \
    {                                                    \
        float m_  = fmaf((ZI), (ZI), (ZR) * (ZR));       \
        float cr_ = fmaf(-(BR), m_, (AR));               \
        float ci_ = fmaf(-(BI), m_, (AI));               \
        (KR) = fmaf(cr_, (ZR), -(ci_ * (ZI)));           \
        (KI) = fmaf(cr_, (ZI),  (ci_ * (ZR)));           \
    }

__global__ __launch_bounds__(256) void hopf_dopri5_kernel(
    const float* __restrict__ re_z, const float* __restrict__ im_z,
    const float* __restrict__ re_a, const float* __restrict__ im_a,
    const float* __restrict__ re_b, const float* __restrict__ im_b,
    const int*  __restrict__ unts_p,
    float* __restrict__ out, int n)
{
    const int t = blockIdx.x * blockDim.x + threadIdx.x;
    const int i = t * 4;                 // 4 elements per thread
    if (i >= n) return;

    // h = float32( (2*pi - 2*pi/unts) / 50 ) -- double, matching the reference
    const int unts = unts_p[0];
    const double t1 = 2.0 * M_PI - 2.0 * M_PI / (double)unts;
    const float h = sbc((float)(t1 / (double)NUM_STEPS));

    // Pre-scaled Dormand-Prince tableau, pinned to SGPRs
    const float hA21 = sbc(h * (float)(1.0/5.0));
    const float hA31 = sbc(h * (float)(3.0/40.0));
    const float hA32 = sbc(h * (float)(9.0/40.0));
    const float hA41 = sbc(h * (float)(44.0/45.0));
    const float hA42 = sbc(h * (float)(-56.0/15.0));
    const float hA43 = sbc(h * (float)(32.0/9.0));
    const float hA51 = sbc(h * (float)(19372.0/6561.0));
    const float hA52 = sbc(h * (float)(-25360.0/2187.0));
    const float hA53 = sbc(h * (float)(64448.0/6561.0));
    const float hA54 = sbc(h * (float)(-212.0/729.0));
    const float hA61 = sbc(h * (float)(9017.0/3168.0));
    const float hA62 = sbc(h * (float)(-355.0/33.0));
    const float hA63 = sbc(h * (float)(46732.0/5247.0));
    const float hA64 = sbc(h * (float)(49.0/176.0));
    const float hA65 = sbc(h * (float)(-5103.0/18656.0));
    const float hB1  = sbc(h * (float)(35.0/384.0));
    const float hB3  = sbc(h * (float)(500.0/1113.0));
    const float hB4  = sbc(h * (float)(125.0/192.0));
    const float hB5  = sbc(h * (float)(-2187.0/6784.0));
    const float hB6  = sbc(h * (float)(11.0/84.0));

    // 16 B/lane coalesced vector loads
    const float4 zr4 = *(const float4*)(re_z + i);
    const float4 zi4 = *(const float4*)(im_z + i);
    const float4 ar4 = *(const float4*)(re_a + i);
    const float4 ai4 = *(const float4*)(im_a + i);
    const float4 br4 = *(const float4*)(re_b + i);
    const float4 bi4 = *(const float4*)(im_b + i);

    float z0r = zr4.x, z1r = zr4.y, z2r = zr4.z, z3r = zr4.w;
    float z0i = zi4.x, z1i = zi4.y, z2i = zi4.z, z3i = zi4.w;

    #pragma unroll 1
    for (int s = 0; s < NUM_STEPS; ++s) {
#define STEP(ZR, ZI, AR, AI, BR, BI)                                            \
        {                                                                       \
            float k1r,k1i,k2r,k2i,k3r,k3i,k4r,k4i,k5r,k5i,k6r,k6i,tr,ti;        \
            FEVAL(ZR, ZI, k1r, k1i, AR, AI, BR, BI)                             \
            tr = fmaf(hA21,k1r, ZR);                                            \
            ti = fmaf(hA21,k1i, ZI);                                            \
            FEVAL(tr, ti, k2r, k2i, AR, AI, BR, BI)                             \
            tr = fmaf(hA31,k1r, fmaf(hA32,k2r, ZR));                            \
            ti = fmaf(hA31,k1i, fmaf(hA32,k2i, ZI));                            \
            FEVAL(tr, ti, k3r, k3i, AR, AI, BR, BI)                             \
            tr = fmaf(hA41,k1r, fmaf(hA42,k2r, fmaf(hA43,k3r, ZR)));            \
            ti = fmaf(hA41,k1i, fmaf(hA42,k2i, fmaf(hA43,k3i, ZI)));            \
            FEVAL(tr, ti, k4r, k4i, AR, AI, BR, BI)                             \
            tr = fmaf(hA51,k1r, fmaf(hA52,k2r, fmaf(hA53,k3r, fmaf(hA54,k4r, ZR)))); \
            ti = fmaf(hA51,k1i, fmaf(hA52,k2i, fmaf(hA53,k3i, fmaf(hA54,k4i, ZI)))); \
            FEVAL(tr, ti, k5r, k5i, AR, AI, BR, BI)                             \
            tr = fmaf(hA61,k1r, fmaf(hA62,k2r, fmaf(hA63,k3r, fmaf(hA64,k4r, fmaf(hA65,k5r, ZR))))); \
            ti = fmaf(hA61,k1i, fmaf(hA62,k2i, fmaf(hA63,k3i, fmaf(hA64,k4i, fmaf(hA65,k5i, ZI))))); \
            FEVAL(tr, ti, k6r, k6i, AR, AI, BR, BI)                             \
            ZR = fmaf(hB1,k1r, fmaf(hB3,k3r, fmaf(hB4,k4r, fmaf(hB5,k5r, fmaf(hB6,k6r, ZR))))); \
            ZI = fmaf(hB1,k1i, fmaf(hB3,k3i, fmaf(hB4,k4i, fmaf(hB5,k5i, fmaf(hB6,k6i, ZI))))); \
        }
        STEP(z0r, z0i, ar4.x, ai4.x, br4.x, bi4.x)
        STEP(z1r, z1i, ar4.y, ai4.y, br4.y, bi4.y)
        STEP(z2r, z2i, ar4.z, ai4.z, br4.z, bi4.z)
        STEP(z3r, z3i, ar4.w, ai4.w, br4.w, bi4.w)
#undef STEP
    }

    // Output: stack([re, im]) -> first n reals, then n imags
    *(float4*)(out + i)     = make_float4(z0r, z1r, z2r, z3r);
    *(float4*)(out + n + i) = make_float4(z0i, z1i, z2i, z3i);
}

extern "C" void kernel_launch(void* const* d_in, const int* in_sizes, int n_in,
                              void* d_out, int out_size, void* d_ws, size_t ws_size,
                              hipStream_t stream) {
    const float* re_z = (const float*)d_in[0];
    const float* im_z = (const float*)d_in[1];
    const float* re_a = (const float*)d_in[2];
    const float* im_a = (const float*)d_in[3];
    const float* re_b = (const float*)d_in[4];
    const float* im_b = (const float*)d_in[5];
    // d_in[6] = stp (unused by the reference)
    const int*   unts = (const int*)d_in[7];
    float* out = (float*)d_out;

    const int n = in_sizes[0];                 // 2048*2048
    const int threads = (n + 3) / 4;           // 4 elements per thread
    const int block = 256;
    const int grid = (threads + block - 1) / block;

    hopf_dopri5_kernel<<<grid, block, 0, stream>>>(re_z, im_z, re_a, im_a,
                                                   re_b, im_b, unts, out, n);
}